// Round 4
// baseline (412.119 us; speedup 1.0000x reference)
//
#include <hip/hip_runtime.h>
#include <hip/hip_fp16.h>

// Deformable RoI pooling (MMCV-style), forward only.
// features: (B=8, C=256, H=168, W=168) fp32 = 231 MB
// rois:     (N=512, 5)  [bidx, x1, y1, x2, y2]
// offset:   (N=512, 2, PH=7, PW=7)
// out:      (N, C, PH, PW) fp32
//
// Round 8 (= round-7 pipeline, spill-proofed):
//  - round-7 post-mortem: VGPR=32 + WRITE_SIZE 72MB (vs 28.7 output) proved
//    the v[7] staging array went to SCRATCH (rule #20). Fix: named scalar
//    registers v0..v6 + fully hand-unrolled LOAD/STORE macros — a named
//    float4 cannot be runtime-indexed, so it cannot spill to local mem.
//  - each block owns PPB_=4 channels; next plane's 7x global_load_dwordx4
//    are issued BEFORE sampling the current plane (issue-early/write-late):
//    HBM latency hides under the LDS gather. Grid 64x8=512 blocks, 2/CU.
//  - folded fp32 weights + clamp-free 4-tap reads vs zero-padded fp16 plane
//    (round-6 algorithm, verified absmax 0.015625).

#define PH_ 7
#define PW_ 7
#define SPP_ 2
#define SS_ 0.0625f
#define TRANS_STD_ 0.1f
#define B_ 8
#define C_ 256
#define H_ 168
#define W_ 168
#define N_ 512
#define HW_ (H_ * W_)            // 28224
#define HW4_ (HW_ / 4)           // 7056 float4s per plane
#define BINS_ (PH_ * PW_)        // 49
#define NSUB_ (SPP_ * SPP_)      // 4
#define BLK_ 1024
#define RPC_ 20                  // rois per chunk (20*49 = 980 <= 1024)
#define PLN_ (HW_ + W_ + 4)      // zero-padded plane (max tap idx = HW_+W_)
#define PPB_ 4                   // channels (planes) per block

// ws layout (ints):
//   counts[8] | lists[8][512] | descA uint4[N][BINS] | descW float4[N][BINS][NSUB]
#define WS_LIST_OFF_   B_
#define WS_DESCA_OFF_I (B_ + B_ * N_)                    // 4104 ints (16B-aligned)
#define DESCA_INTS_    (N_ * BINS_ * 4)                  // 100352 ints
#define WS_DESCW_OFF_I (WS_DESCA_OFF_I + DESCA_INTS_)    // 104456 ints (16B-aligned)
#define DESCW_FLOATS_  (N_ * BINS_ * NSUB_ * 4)          // 401408 floats
#define WS_NEEDED_     ((size_t)(WS_DESCW_OFF_I + DESCW_FLOATS_) * 4)

// ---------------- prologue 1: bucket rois by image ----------------
__global__ __launch_bounds__(512) void build_roi_lists(
    const float* __restrict__ rois, int* __restrict__ ws)
{
    const int r = threadIdx.x;              // 512 threads, 1 block
    if (r < B_) ws[r] = 0;                  // ws is poisoned each call
    __syncthreads();
    const int b = (int)rois[r * 5 + 0];
    const int pos = atomicAdd(&ws[b], 1);
    ws[WS_LIST_OFF_ + b * N_ + pos] = r;
}

// ---------------- prologue 2: folded-weight descriptors ----------------
// one block per roi; lanes 0..48 = bins.
__global__ __launch_bounds__(64) void build_desc(
    const float* __restrict__ rois,
    const float* __restrict__ offset,
    int* __restrict__ ws)
{
    const int r   = blockIdx.x;
    const int bin = threadIdx.x;
    if (bin >= BINS_) return;
    const int ph = bin / PW_;
    const int pw = bin - ph * PW_;

    const float x1r = rois[r * 5 + 1];
    const float y1r = rois[r * 5 + 2];
    const float x2r = rois[r * 5 + 3];
    const float y2r = rois[r * 5 + 4];

    const float sw    = x1r * SS_ - 0.5f;
    const float sh    = y1r * SS_ - 0.5f;
    const float rw    = fmaxf((x2r + 1.0f) * SS_ - 0.5f - sw, 0.1f);
    const float rh    = fmaxf((y2r + 1.0f) * SS_ - 0.5f - sh, 0.1f);
    const float bin_w = rw * (1.0f / PW_);
    const float bin_h = rh * (1.0f / PH_);
    const float sub_w = bin_w * (1.0f / SPP_);
    const float sub_h = bin_h * (1.0f / SPP_);

    const float offx = offset[((r * 2 + 0) * PH_ + ph) * PW_ + pw] * TRANS_STD_;
    const float offy = offset[((r * 2 + 1) * PH_ + ph) * PW_ + pw] * TRANS_STD_;

    const float bx = sw + (float)pw * bin_w + offx * rw;
    const float by = sh + (float)ph * bin_h + offy * rh;

    unsigned idx[NSUB_];
    float w00[NSUB_], w01[NSUB_], w10[NSUB_], w11[NSUB_];
    int   vals[NSUB_];
    int   cnt = 0;
#pragma unroll
    for (int s = 0; s < NSUB_; ++s) {
        const int ihs = s >> 1;             // sub index order: (ih, iw)
        const int iws = s & 1;
        const float x = bx + ((float)iws + 0.5f) * sub_w;
        const float y = by + ((float)ihs + 0.5f) * sub_h;
        const int valid = (x > -0.5f) && (x < (float)W_ - 0.5f) &&
                          (y > -0.5f) && (y < (float)H_ - 0.5f);
        const float xc = fminf(fmaxf(x, 0.0f), (float)(W_ - 1));
        const float yc = fminf(fmaxf(y, 0.0f), (float)(H_ - 1));
        const float x0f = floorf(xc);
        const float y0f = floorf(yc);
        const int x0 = (int)x0f;
        const int y0 = (int)y0f;
        const float lx = xc - x0f;
        const float ly = yc - y0f;
        // NOTE: if lx>0 then x0 <= W-2 (floor of xc<W-1), so the +1 neighbor
        // is in-range whenever its weight is nonzero; same for ly/y0.
        idx[s] = (unsigned)(y0 * W_ + x0);
        w00[s] = (1.0f - ly) * (1.0f - lx);
        w01[s] = (1.0f - ly) * lx;
        w10[s] = ly * (1.0f - lx);
        w11[s] = ly * lx;
        vals[s] = valid;
        cnt += valid;
    }
    const float inv = (cnt > 0) ? (1.0f / (float)cnt) : 0.0f;

    uint4*  descA = reinterpret_cast<uint4*> (ws + WS_DESCA_OFF_I);
    float4* descW = reinterpret_cast<float4*>(ws + WS_DESCW_OFF_I);

    const int rb = r * BINS_ + bin;
#pragma unroll
    for (int s = 0; s < NSUB_; ++s) {
        const float f = vals[s] ? inv : 0.0f;
        float4 w;
        w.x = w00[s] * f;
        w.y = w01[s] * f;
        w.z = w10[s] * f;
        w.w = w11[s] * f;
        descW[(size_t)rb * NSUB_ + s] = w;
    }
    uint4 a4;
    a4.x = idx[0]; a4.y = idx[1]; a4.z = idx[2]; a4.w = idx[3];
    descA[rb] = a4;
}

// ---------------- main kernel (pipelined over PPB_ planes) ----------------
// Staging lives in NAMED float4 scalars v0..v6 — impossible to scratch-spill.

#define LOADI_(i, vv)                                                 \
    { const int ii = tid + (i) * BLK_; vv = f4[ii < HW4_ ? ii : 0]; }

#define LOAD_PLANE(cc)                                                \
    do {                                                              \
        const float4* __restrict__ f4 = fbase + (size_t)(cc) * HW4_;  \
        LOADI_(0, v0) LOADI_(1, v1) LOADI_(2, v2) LOADI_(3, v3)       \
        LOADI_(4, v4) LOADI_(5, v5) LOADI_(6, v6)                     \
    } while (0)

#define STOREI_(i, vv)                                                \
    { const int ii = tid + (i) * BLK_;                                \
      if (ii < HW4_) {                                                \
          union { __half2 h[2]; float2 f2; } u;                       \
          u.h[0].x = __float2half(vv.x); u.h[0].y = __float2half(vv.y);\
          u.h[1].x = __float2half(vv.z); u.h[1].y = __float2half(vv.w);\
          *reinterpret_cast<float2*>(&plane[ii * 4]) = u.f2;          \
      } }

#define STORE_PLANE()                                                 \
    do {                                                              \
        STOREI_(0, v0) STOREI_(1, v1) STOREI_(2, v2) STOREI_(3, v3)   \
        STOREI_(4, v4) STOREI_(5, v5) STOREI_(6, v6)                  \
    } while (0)

__global__ __launch_bounds__(BLK_, 8) void droi_pool_lds(
    const float* __restrict__ features,
    float* __restrict__ out,
    const int* __restrict__ ws)
{
    __shared__ __half plane[PLN_];          // 56,792 B -> 2 blocks/CU @1024 thr

    const int c0  = blockIdx.x * PPB_;      // first channel of this block
    const int b   = blockIdx.y;             // image
    const int tid = threadIdx.x;

    const float4* __restrict__ fbase =
        reinterpret_cast<const float4*>(features + (size_t)b * C_ * HW_);

    float4 v0, v1, v2, v3, v4, v5, v6;

    // ---- prologue: plane c0 -> LDS; zero-pad tail once ----
    LOAD_PLANE(c0);
    for (int i = HW_ + tid; i < PLN_; i += BLK_) plane[i] = __float2half(0.0f);
    STORE_PLANE();
    __syncthreads();

    const int cnt_b = ws[b];
    const int* __restrict__ list = ws + WS_LIST_OFF_ + b * N_;
    const uint4* __restrict__ descA =
        reinterpret_cast<const uint4*>(ws + WS_DESCA_OFF_I);
    const float4* __restrict__ descW =
        reinterpret_cast<const float4*>(ws + WS_DESCW_OFF_I);

    const int q   = tid / BINS_;            // roi slot within chunk
    const int bin = tid - q * BINS_;        // 0..48
    const bool lane_ok = (q < RPC_);

#pragma unroll
    for (int p = 0; p < PPB_; ++p) {
        const int c = c0 + p;

        // issue next plane's global loads BEFORE sampling: their ~900-cycle
        // latency hides under phase 2; the compiler's vmcnt drain sits at the
        // STORE_PLANE below, after sampling is done.
        if (p + 1 < PPB_) LOAD_PLANE(c + 1);

        // ---- phase 2: rois of image b sample plane c via descriptors ----
        for (int base = 0; base < cnt_b; base += RPC_) {
            const int idx    = base + q;
            const bool active = lane_ok && (idx < cnt_b);
            if (active) {
                const int r  = list[idx];
                const int rb = r * BINS_ + bin;

                const uint4 a4 = descA[rb];
                const float4* __restrict__ wp = descW + (size_t)rb * NSUB_;

                float acc = 0.0f;
#pragma unroll
                for (int s = 0; s < NSUB_; ++s) {
                    const float4 w = wp[s];
                    const int a = (int)((&a4.x)[s]);
                    const float f00 = __half2float(plane[a]);
                    const float f01 = __half2float(plane[a + 1]);
                    const float f10 = __half2float(plane[a + W_]);
                    const float f11 = __half2float(plane[a + W_ + 1]);
                    acc += w.x * f00 + w.y * f01 + w.z * f10 + w.w * f11;
                }
                out[((size_t)r * C_ + c) * BINS_ + bin] = acc;
            }
        }

        __syncthreads();                    // all waves done reading plane c
        if (p + 1 < PPB_) STORE_PLANE();    // convert + ds_write plane c+1
        __syncthreads();                    // plane c+1 visible
    }
}

// ---------------- fallback (round-1 kernel) if ws too small ----------------
__global__ __launch_bounds__(64) void droi_pool_fallback(
    const float* __restrict__ features,
    const float* __restrict__ rois,
    const float* __restrict__ offset,
    float* __restrict__ out)
{
    const int blk  = blockIdx.x;
    const int n    = blk >> 8;
    const int c    = blk & 255;
    const int lane = threadIdx.x;
    if (lane >= BINS_) return;
    const int ph = lane / PW_;
    const int pw = lane % PW_;

    const float r0  = rois[n * 5 + 0];
    const float x1r = rois[n * 5 + 1];
    const float y1r = rois[n * 5 + 2];
    const float x2r = rois[n * 5 + 3];
    const float y2r = rois[n * 5 + 4];
    const int   b   = (int)r0;

    const float sw    = x1r * SS_ - 0.5f;
    const float sh    = y1r * SS_ - 0.5f;
    const float rw    = fmaxf((x2r + 1.0f) * SS_ - 0.5f - sw, 0.1f);
    const float rh    = fmaxf((y2r + 1.0f) * SS_ - 0.5f - sh, 0.1f);
    const float bin_w = rw / PW_;
    const float bin_h = rh / PH_;
    const float sub_w = bin_w / SPP_;
    const float sub_h = bin_h / SPP_;

    const float offx = offset[((n * 2 + 0) * PH_ + ph) * PW_ + pw] * TRANS_STD_;
    const float offy = offset[((n * 2 + 1) * PH_ + ph) * PW_ + pw] * TRANS_STD_;

    const float bx = sw + (float)pw * bin_w + offx * rw;
    const float by = sh + (float)ph * bin_h + offy * rh;

    const float* __restrict__ f =
        features + (size_t)(b * C_ + c) * (size_t)HW_;

    float s = 0.0f;
    int cnt = 0;
#pragma unroll
    for (int ihs = 0; ihs < SPP_; ++ihs) {
#pragma unroll
        for (int iws = 0; iws < SPP_; ++iws) {
            const float x = bx + ((float)iws + 0.5f) * sub_w;
            const float y = by + ((float)ihs + 0.5f) * sub_h;
            const bool valid = (x > -0.5f) && (x < (float)W_ - 0.5f) &&
                               (y > -0.5f) && (y < (float)H_ - 0.5f);
            const float xc = fminf(fmaxf(x, 0.0f), (float)(W_ - 1));
            const float yc = fminf(fmaxf(y, 0.0f), (float)(H_ - 1));
            const float x0f = floorf(xc);
            const float y0f = floorf(yc);
            const float lx = xc - x0f;
            const float ly = yc - y0f;
            const int x0 = (int)x0f;
            const int y0 = (int)y0f;
            const int x1i = min(x0 + 1, W_ - 1);
            const int y1i = min(y0 + 1, H_ - 1);
            const float f00 = f[y0  * W_ + x0 ];
            const float f01 = f[y0  * W_ + x1i];
            const float f10 = f[y1i * W_ + x0 ];
            const float f11 = f[y1i * W_ + x1i];
            const float v = (1.0f - ly) * (1.0f - lx) * f00 +
                            (1.0f - ly) * lx          * f01 +
                            ly          * (1.0f - lx) * f10 +
                            ly          * lx          * f11;
            if (valid) { s += v; cnt += 1; }
        }
    }
    const float res = (cnt > 0) ? (s / (float)cnt) : 0.0f;
    out[(size_t)(n * C_ + c) * BINS_ + lane] = res;
}

extern "C" void kernel_launch(void* const* d_in, const int* in_sizes, int n_in,
                              void* d_out, int out_size, void* d_ws, size_t ws_size,
                              hipStream_t stream) {
    const float* features = (const float*)d_in[0];
    const float* rois     = (const float*)d_in[1];
    const float* offset   = (const float*)d_in[2];
    float*       out      = (float*)d_out;

    if (ws_size >= WS_NEEDED_) {
        int* ws = (int*)d_ws;
        hipLaunchKernelGGL(build_roi_lists, dim3(1), dim3(N_), 0, stream,
                           rois, ws);
        hipLaunchKernelGGL(build_desc, dim3(N_), dim3(64), 0, stream,
                           rois, offset, ws);
        // grid: x = channel-group (64), y = image (8); 512 blocks, 2/CU,
        // all resident; each block pipelines PPB_=4 planes.
        hipLaunchKernelGGL(droi_pool_lds, dim3(C_ / PPB_, B_), dim3(BLK_),
                           0, stream, features, out, ws);
    } else {
        hipLaunchKernelGGL(droi_pool_fallback, dim3(N_ * C_), dim3(64), 0, stream,
                           features, rois, offset, out);
    }
}

// Round 5
// 381.608 us; speedup vs baseline: 1.0800x; 1.0800x over previous
//
#include <hip/hip_runtime.h>
#include <hip/hip_fp16.h>

// Deformable RoI pooling (MMCV-style), forward only.
// features: (B=8, C=256, H=168, W=168) fp32 = 231 MB
// rois:     (N=512, 5)  [bidx, x1, y1, x2, y2]
// offset:   (N=512, 2, PH=7, PW=7)
// out:      (N, C, PH, PW) fp32
//
// Round 9: producer/consumer wave split, double-buffered LDS plane.
//  - rounds 7/8 post-mortem: register-staged prefetch spills no matter how
//    it's written (VGPR=32 + 45MB scratch writes both rounds) because the
//    staging regs must live across the runtime-trip sampling loop + barriers.
//    Abandoned.
//  - new: waves 0..7 stream plane p+1 into LDS buffer B (simple streaming
//    loop, liveness of 1 float4 -> nothing to spill) while waves 8..15
//    sample plane p from buffer A. One __syncthreads per plane. HBM never
//    idles waiting for sampling; sampling never waits for HBM.
//  - LDS 2 x 56.8 KB = 113.6 KB -> 1 block/CU, 16 waves. Grid 32x8 = 256
//    blocks = 1/CU, each owns CPB_=8 channels; single generation.
//  - prologue kernels merged into one launch (desc blocks + list block are
//    independent).
//  - folded fp32 weights + clamp-free 4-tap reads vs zero-padded fp16 plane
//    (round-6 algorithm, verified absmax 0.015625).

#define PH_ 7
#define PW_ 7
#define SPP_ 2
#define SS_ 0.0625f
#define TRANS_STD_ 0.1f
#define B_ 8
#define C_ 256
#define H_ 168
#define W_ 168
#define N_ 512
#define HW_ (H_ * W_)            // 28224
#define HW4_ (HW_ / 4)           // 7056 float4s per plane
#define BINS_ (PH_ * PW_)        // 49
#define NSUB_ (SPP_ * SPP_)      // 4
#define BLK_ 1024
#define PLN_ (HW_ + W_ + 4)      // zero-padded plane (max tap idx = HW_+W_)
#define CPB_ 8                   // channels per block
#define NPROD_ 512               // producer threads (waves 0..7)
#define CRPC_ 10                 // rois per consumer chunk (10*49=490 <= 512)

// ws layout (ints):
//   counts[8] | lists[8][512] | descA uint4[N][BINS] | descW float4[N][BINS][NSUB]
#define WS_LIST_OFF_   B_
#define WS_DESCA_OFF_I (B_ + B_ * N_)                    // 4104 ints (16B-aligned)
#define DESCA_INTS_    (N_ * BINS_ * 4)                  // 100352 ints
#define WS_DESCW_OFF_I (WS_DESCA_OFF_I + DESCA_INTS_)    // 104456 ints (16B-aligned)
#define DESCW_FLOATS_  (N_ * BINS_ * NSUB_ * 4)          // 401408 floats
#define WS_NEEDED_     ((size_t)(WS_DESCW_OFF_I + DESCW_FLOATS_) * 4)

// ---------------- merged prologue ----------------
// blocks 0..N_-1: folded-weight descriptors for roi r (lanes 0..48 = bins).
// block  N_:      zero counts + bucket rois by image (threads stride rois).
__global__ __launch_bounds__(64) void build_all(
    const float* __restrict__ rois,
    const float* __restrict__ offset,
    int* __restrict__ ws)
{
    const int blk = blockIdx.x;
    const int t   = threadIdx.x;

    if (blk == N_) {                        // ---- roi list block ----
        if (t < B_) ws[t] = 0;              // ws is poisoned each call
        __syncthreads();
        for (int r = t; r < N_; r += 64) {
            const int b = (int)rois[r * 5 + 0];
            const int pos = atomicAdd(&ws[b], 1);
            ws[WS_LIST_OFF_ + b * N_ + pos] = r;
        }
        return;
    }

    // ---- descriptor block for roi r = blk ----
    const int r   = blk;
    const int bin = t;
    if (bin >= BINS_) return;
    const int ph = bin / PW_;
    const int pw = bin - ph * PW_;

    const float x1r = rois[r * 5 + 1];
    const float y1r = rois[r * 5 + 2];
    const float x2r = rois[r * 5 + 3];
    const float y2r = rois[r * 5 + 4];

    const float sw    = x1r * SS_ - 0.5f;
    const float sh    = y1r * SS_ - 0.5f;
    const float rw    = fmaxf((x2r + 1.0f) * SS_ - 0.5f - sw, 0.1f);
    const float rh    = fmaxf((y2r + 1.0f) * SS_ - 0.5f - sh, 0.1f);
    const float bin_w = rw * (1.0f / PW_);
    const float bin_h = rh * (1.0f / PH_);
    const float sub_w = bin_w * (1.0f / SPP_);
    const float sub_h = bin_h * (1.0f / SPP_);

    const float offx = offset[((r * 2 + 0) * PH_ + ph) * PW_ + pw] * TRANS_STD_;
    const float offy = offset[((r * 2 + 1) * PH_ + ph) * PW_ + pw] * TRANS_STD_;

    const float bx = sw + (float)pw * bin_w + offx * rw;
    const float by = sh + (float)ph * bin_h + offy * rh;

    unsigned idx[NSUB_];
    float w00[NSUB_], w01[NSUB_], w10[NSUB_], w11[NSUB_];
    int   vals[NSUB_];
    int   cnt = 0;
#pragma unroll
    for (int s = 0; s < NSUB_; ++s) {
        const int ihs = s >> 1;             // sub index order: (ih, iw)
        const int iws = s & 1;
        const float x = bx + ((float)iws + 0.5f) * sub_w;
        const float y = by + ((float)ihs + 0.5f) * sub_h;
        const int valid = (x > -0.5f) && (x < (float)W_ - 0.5f) &&
                          (y > -0.5f) && (y < (float)H_ - 0.5f);
        const float xc = fminf(fmaxf(x, 0.0f), (float)(W_ - 1));
        const float yc = fminf(fmaxf(y, 0.0f), (float)(H_ - 1));
        const float x0f = floorf(xc);
        const float y0f = floorf(yc);
        const int x0 = (int)x0f;
        const int y0 = (int)y0f;
        const float lx = xc - x0f;
        const float ly = yc - y0f;
        // NOTE: if lx>0 then x0 <= W-2 (floor of xc<W-1), so the +1 neighbor
        // is in-range whenever its weight is nonzero; same for ly/y0.
        idx[s] = (unsigned)(y0 * W_ + x0);
        w00[s] = (1.0f - ly) * (1.0f - lx);
        w01[s] = (1.0f - ly) * lx;
        w10[s] = ly * (1.0f - lx);
        w11[s] = ly * lx;
        vals[s] = valid;
        cnt += valid;
    }
    const float inv = (cnt > 0) ? (1.0f / (float)cnt) : 0.0f;

    uint4*  descA = reinterpret_cast<uint4*> (ws + WS_DESCA_OFF_I);
    float4* descW = reinterpret_cast<float4*>(ws + WS_DESCW_OFF_I);

    const int rb = r * BINS_ + bin;
#pragma unroll
    for (int s = 0; s < NSUB_; ++s) {
        const float f = vals[s] ? inv : 0.0f;
        float4 w;
        w.x = w00[s] * f;
        w.y = w01[s] * f;
        w.z = w10[s] * f;
        w.w = w11[s] * f;
        descW[(size_t)rb * NSUB_ + s] = w;
    }
    uint4 a4;
    a4.x = idx[0]; a4.y = idx[1]; a4.z = idx[2]; a4.w = idx[3];
    descA[rb] = a4;
}

// ---------------- main kernel: producer/consumer over CPB_ planes ----------
__global__ __launch_bounds__(BLK_, 4) void droi_pool_pc(
    const float* __restrict__ features,
    float* __restrict__ out,
    const int* __restrict__ ws)
{
    __shared__ __half bufs[2][PLN_];        // 2 x 56,792 B = 113.6 KB -> 1/CU

    const int c0  = blockIdx.x * CPB_;      // first channel of this block
    const int b   = blockIdx.y;             // image
    const int tid = threadIdx.x;

    const float4* __restrict__ fbase =
        reinterpret_cast<const float4*>(features + (size_t)b * C_ * HW_);

    // zero both pad tails once (producers never touch [HW_, PLN_))
    for (int i = HW_ + tid; i < PLN_; i += BLK_) {
        bufs[0][i] = __float2half(0.0f);
        bufs[1][i] = __float2half(0.0f);
    }
    // stage plane c0 into bufs[0] with ALL 1024 threads (fast start)
    {
        const float4* __restrict__ f4 = fbase + (size_t)c0 * HW4_;
        for (int i = tid; i < HW4_; i += BLK_) {
            const float4 v = f4[i];
            union { __half2 h[2]; float2 f2; } u;
            u.h[0].x = __float2half(v.x); u.h[0].y = __float2half(v.y);
            u.h[1].x = __float2half(v.z); u.h[1].y = __float2half(v.w);
            *reinterpret_cast<float2*>(&bufs[0][i * 4]) = u.f2;
        }
    }
    __syncthreads();

    const int cnt_b = ws[b];
    const int* __restrict__ list = ws + WS_LIST_OFF_ + b * N_;
    const uint4* __restrict__ descA =
        reinterpret_cast<const uint4*>(ws + WS_DESCA_OFF_I);
    const float4* __restrict__ descW =
        reinterpret_cast<const float4*>(ws + WS_DESCW_OFF_I);

    const bool consumer = (tid >= NPROD_);  // waves 8..15
    const int  t   = tid - NPROD_;          // consumer index (>=0 iff consumer)
    const int  q   = consumer ? (t / BINS_) : 0;   // roi slot within chunk
    const int  bin = consumer ? (t - q * BINS_) : 0;
    const bool lane_ok = consumer && (q < CRPC_);

    for (int p = 0; p < CPB_; ++p) {
        const int c = c0 + p;
        const __half* __restrict__ cur = bufs[p & 1];
        __half*       __restrict__ nxt = bufs[(p & 1) ^ 1];

        if (!consumer) {
            // ---- producer waves: stream plane c+1 into the other buffer ----
            if (p + 1 < CPB_) {
                const float4* __restrict__ f4 = fbase + (size_t)(c + 1) * HW4_;
                for (int i = tid; i < HW4_; i += NPROD_) {
                    const float4 v = f4[i];
                    union { __half2 h[2]; float2 f2; } u;
                    u.h[0].x = __float2half(v.x); u.h[0].y = __float2half(v.y);
                    u.h[1].x = __float2half(v.z); u.h[1].y = __float2half(v.w);
                    *reinterpret_cast<float2*>(&nxt[i * 4]) = u.f2;
                }
            }
        } else {
            // ---- consumer waves: sample plane c via folded descriptors ----
            for (int base = 0; base < cnt_b; base += CRPC_) {
                const int idx = base + q;
                if (lane_ok && (idx < cnt_b)) {
                    const int r  = list[idx];
                    const int rb = r * BINS_ + bin;

                    const uint4 a4 = descA[rb];
                    const float4* __restrict__ wp = descW + (size_t)rb * NSUB_;

                    float acc = 0.0f;
#pragma unroll
                    for (int s = 0; s < NSUB_; ++s) {
                        const float4 w = wp[s];
                        const int a = (int)((&a4.x)[s]);
                        const float f00 = __half2float(cur[a]);
                        const float f01 = __half2float(cur[a + 1]);
                        const float f10 = __half2float(cur[a + W_]);
                        const float f11 = __half2float(cur[a + W_ + 1]);
                        acc += w.x * f00 + w.y * f01 + w.z * f10 + w.w * f11;
                    }
                    out[((size_t)r * C_ + c) * BINS_ + bin] = acc;
                }
            }
        }

        __syncthreads();                    // plane c consumed; plane c+1 ready
    }
}

// ---------------- fallback (round-1 kernel) if ws too small ----------------
__global__ __launch_bounds__(64) void droi_pool_fallback(
    const float* __restrict__ features,
    const float* __restrict__ rois,
    const float* __restrict__ offset,
    float* __restrict__ out)
{
    const int blk  = blockIdx.x;
    const int n    = blk >> 8;
    const int c    = blk & 255;
    const int lane = threadIdx.x;
    if (lane >= BINS_) return;
    const int ph = lane / PW_;
    const int pw = lane % PW_;

    const float r0  = rois[n * 5 + 0];
    const float x1r = rois[n * 5 + 1];
    const float y1r = rois[n * 5 + 2];
    const float x2r = rois[n * 5 + 3];
    const float y2r = rois[n * 5 + 4];
    const int   b   = (int)r0;

    const float sw    = x1r * SS_ - 0.5f;
    const float sh    = y1r * SS_ - 0.5f;
    const float rw    = fmaxf((x2r + 1.0f) * SS_ - 0.5f - sw, 0.1f);
    const float rh    = fmaxf((y2r + 1.0f) * SS_ - 0.5f - sh, 0.1f);
    const float bin_w = rw / PW_;
    const float bin_h = rh / PH_;
    const float sub_w = bin_w / SPP_;
    const float sub_h = bin_h / SPP_;

    const float offx = offset[((n * 2 + 0) * PH_ + ph) * PW_ + pw] * TRANS_STD_;
    const float offy = offset[((n * 2 + 1) * PH_ + ph) * PW_ + pw] * TRANS_STD_;

    const float bx = sw + (float)pw * bin_w + offx * rw;
    const float by = sh + (float)ph * bin_h + offy * rh;

    const float* __restrict__ f =
        features + (size_t)(b * C_ + c) * (size_t)HW_;

    float s = 0.0f;
    int cnt = 0;
#pragma unroll
    for (int ihs = 0; ihs < SPP_; ++ihs) {
#pragma unroll
        for (int iws = 0; iws < SPP_; ++iws) {
            const float x = bx + ((float)iws + 0.5f) * sub_w;
            const float y = by + ((float)ihs + 0.5f) * sub_h;
            const bool valid = (x > -0.5f) && (x < (float)W_ - 0.5f) &&
                               (y > -0.5f) && (y < (float)H_ - 0.5f);
            const float xc = fminf(fmaxf(x, 0.0f), (float)(W_ - 1));
            const float yc = fminf(fmaxf(y, 0.0f), (float)(H_ - 1));
            const float x0f = floorf(xc);
            const float y0f = floorf(yc);
            const float lx = xc - x0f;
            const float ly = yc - y0f;
            const int x0 = (int)x0f;
            const int y0 = (int)y0f;
            const int x1i = min(x0 + 1, W_ - 1);
            const int y1i = min(y0 + 1, H_ - 1);
            const float f00 = f[y0  * W_ + x0 ];
            const float f01 = f[y0  * W_ + x1i];
            const float f10 = f[y1i * W_ + x0 ];
            const float f11 = f[y1i * W_ + x1i];
            const float v = (1.0f - ly) * (1.0f - lx) * f00 +
                            (1.0f - ly) * lx          * f01 +
                            ly          * (1.0f - lx) * f10 +
                            ly          * lx          * f11;
            if (valid) { s += v; cnt += 1; }
        }
    }
    const float res = (cnt > 0) ? (s / (float)cnt) : 0.0f;
    out[(size_t)(n * C_ + c) * BINS_ + lane] = res;
}

extern "C" void kernel_launch(void* const* d_in, const int* in_sizes, int n_in,
                              void* d_out, int out_size, void* d_ws, size_t ws_size,
                              hipStream_t stream) {
    const float* features = (const float*)d_in[0];
    const float* rois     = (const float*)d_in[1];
    const float* offset   = (const float*)d_in[2];
    float*       out      = (float*)d_out;

    if (ws_size >= WS_NEEDED_) {
        int* ws = (int*)d_ws;
        // one merged prologue launch: desc blocks 0..N_-1, list block N_
        hipLaunchKernelGGL(build_all, dim3(N_ + 1), dim3(64), 0, stream,
                           rois, offset, ws);
        // grid: x = channel-group (32), y = image (8); 256 blocks, 1/CU
        // (113.6 KB LDS), 16 waves each; producer waves stream plane p+1
        // while consumer waves sample plane p.
        hipLaunchKernelGGL(droi_pool_pc, dim3(C_ / CPB_, B_), dim3(BLK_),
                           0, stream, features, out, ws);
    } else {
        hipLaunchKernelGGL(droi_pool_fallback, dim3(N_ * C_), dim3(64), 0, stream,
                           features, rois, offset, out);
    }
}

// Round 6
// 355.990 us; speedup vs baseline: 1.1577x; 1.0720x over previous
//
#include <hip/hip_runtime.h>
#include <hip/hip_fp16.h>

// Deformable RoI pooling (MMCV-style), forward only.
// features: (B=8, C=256, H=168, W=168) fp32 = 231 MB
// rois:     (N=512, 5)  [bidx, x1, y1, x2, y2]
// offset:   (N=512, 2, PH=7, PW=7)
// out:      (N, C, PH, PW) fp32
//
// Round 10: global_load_lds (width=16) staging, fp32 plane, serial per plane.
//  - round-9 post-mortem: all register/LDS staging variants pin feature-read
//    BW at ~1.4-1.6 TB/s because the {load->wait->cvt->ds_write} loop keeps
//    ~2 KB in flight per CU (need ~9 KB for 6.3 TB/s). Fix: fire-and-forget
//    global_load_lds dwordx4 — each thread issues all 7 plane loads with no
//    reg destination, drained once by __syncthreads' vmcnt(0).
//  - plane staged fp32 (gload_lds cannot convert): 113.6 KB LDS, 1 block/CU,
//    16 waves; grid 32x8 = 256 blocks = exactly 1/CU, CPB_=8 channels each.
//    fp32 taps also remove the fp16 quantization error.
//  - LDS dest of gload_lds is wave-uniform base + lane*16 (m104); our layout
//    slot = tid + i*1024 is exactly linear per wave -> constraint satisfied.
//  - folded fp32 weights + clamp-free 4-tap reads vs zero-padded plane
//    (round-6 algorithm); merged single-launch prologue (round 9).

#define PH_ 7
#define PW_ 7
#define SPP_ 2
#define SS_ 0.0625f
#define TRANS_STD_ 0.1f
#define B_ 8
#define C_ 256
#define H_ 168
#define W_ 168
#define N_ 512
#define HW_ (H_ * W_)            // 28224
#define HW4_ (HW_ / 4)           // 7056 float4s per plane
#define BINS_ (PH_ * PW_)        // 49
#define NSUB_ (SPP_ * SPP_)      // 4
#define BLK_ 1024
#define RPC_ 20                  // rois per chunk (20*49 = 980 <= 1024)
#define PLN_ (HW_ + W_ + 4)      // zero-padded plane (max tap idx = HW_+W_)
#define CPB_ 8                   // channels per block
#define FULL_ROUNDS_ 6           // 6*1024 = 6144 full slots
#define TAIL_THREADS_ (HW4_ - FULL_ROUNDS_ * BLK_)   // 912

// ws layout (ints):
//   counts[8] | lists[8][512] | descA uint4[N][BINS] | descW float4[N][BINS][NSUB]
#define WS_LIST_OFF_   B_
#define WS_DESCA_OFF_I (B_ + B_ * N_)                    // 4104 ints (16B-aligned)
#define DESCA_INTS_    (N_ * BINS_ * 4)                  // 100352 ints
#define WS_DESCW_OFF_I (WS_DESCA_OFF_I + DESCA_INTS_)    // 104456 ints (16B-aligned)
#define DESCW_FLOATS_  (N_ * BINS_ * NSUB_ * 4)          // 401408 floats
#define WS_NEEDED_     ((size_t)(WS_DESCW_OFF_I + DESCW_FLOATS_) * 4)

// async 16B global -> LDS (gfx950). size must be a literal.
__device__ __forceinline__ void gload16(const void* g, void* l)
{
    __builtin_amdgcn_global_load_lds(
        (const __attribute__((address_space(1))) unsigned int*)g,
        (__attribute__((address_space(3))) unsigned int*)l,
        16, 0, 0);
}

// ---------------- merged prologue ----------------
// blocks 0..N_-1: folded-weight descriptors for roi r (lanes 0..48 = bins).
// block  N_:      zero counts + bucket rois by image.
__global__ __launch_bounds__(64) void build_all(
    const float* __restrict__ rois,
    const float* __restrict__ offset,
    int* __restrict__ ws)
{
    const int blk = blockIdx.x;
    const int t   = threadIdx.x;

    if (blk == N_) {                        // ---- roi list block ----
        if (t < B_) ws[t] = 0;              // ws is poisoned each call
        __syncthreads();
        for (int r = t; r < N_; r += 64) {
            const int b = (int)rois[r * 5 + 0];
            const int pos = atomicAdd(&ws[b], 1);
            ws[WS_LIST_OFF_ + b * N_ + pos] = r;
        }
        return;
    }

    // ---- descriptor block for roi r = blk ----
    const int r   = blk;
    const int bin = t;
    if (bin >= BINS_) return;
    const int ph = bin / PW_;
    const int pw = bin - ph * PW_;

    const float x1r = rois[r * 5 + 1];
    const float y1r = rois[r * 5 + 2];
    const float x2r = rois[r * 5 + 3];
    const float y2r = rois[r * 5 + 4];

    const float sw    = x1r * SS_ - 0.5f;
    const float sh    = y1r * SS_ - 0.5f;
    const float rw    = fmaxf((x2r + 1.0f) * SS_ - 0.5f - sw, 0.1f);
    const float rh    = fmaxf((y2r + 1.0f) * SS_ - 0.5f - sh, 0.1f);
    const float bin_w = rw * (1.0f / PW_);
    const float bin_h = rh * (1.0f / PH_);
    const float sub_w = bin_w * (1.0f / SPP_);
    const float sub_h = bin_h * (1.0f / SPP_);

    const float offx = offset[((r * 2 + 0) * PH_ + ph) * PW_ + pw] * TRANS_STD_;
    const float offy = offset[((r * 2 + 1) * PH_ + ph) * PW_ + pw] * TRANS_STD_;

    const float bx = sw + (float)pw * bin_w + offx * rw;
    const float by = sh + (float)ph * bin_h + offy * rh;

    unsigned idx[NSUB_];
    float w00[NSUB_], w01[NSUB_], w10[NSUB_], w11[NSUB_];
    int   vals[NSUB_];
    int   cnt = 0;
#pragma unroll
    for (int s = 0; s < NSUB_; ++s) {
        const int ihs = s >> 1;             // sub index order: (ih, iw)
        const int iws = s & 1;
        const float x = bx + ((float)iws + 0.5f) * sub_w;
        const float y = by + ((float)ihs + 0.5f) * sub_h;
        const int valid = (x > -0.5f) && (x < (float)W_ - 0.5f) &&
                          (y > -0.5f) && (y < (float)H_ - 0.5f);
        const float xc = fminf(fmaxf(x, 0.0f), (float)(W_ - 1));
        const float yc = fminf(fmaxf(y, 0.0f), (float)(H_ - 1));
        const float x0f = floorf(xc);
        const float y0f = floorf(yc);
        const int x0 = (int)x0f;
        const int y0 = (int)y0f;
        const float lx = xc - x0f;
        const float ly = yc - y0f;
        // NOTE: if lx>0 then x0 <= W-2 (floor of xc<W-1), so the +1 neighbor
        // is in-range whenever its weight is nonzero; same for ly/y0.
        idx[s] = (unsigned)(y0 * W_ + x0);
        w00[s] = (1.0f - ly) * (1.0f - lx);
        w01[s] = (1.0f - ly) * lx;
        w10[s] = ly * (1.0f - lx);
        w11[s] = ly * lx;
        vals[s] = valid;
        cnt += valid;
    }
    const float inv = (cnt > 0) ? (1.0f / (float)cnt) : 0.0f;

    uint4*  descA = reinterpret_cast<uint4*> (ws + WS_DESCA_OFF_I);
    float4* descW = reinterpret_cast<float4*>(ws + WS_DESCW_OFF_I);

    const int rb = r * BINS_ + bin;
#pragma unroll
    for (int s = 0; s < NSUB_; ++s) {
        const float f = vals[s] ? inv : 0.0f;
        float4 w;
        w.x = w00[s] * f;
        w.y = w01[s] * f;
        w.z = w10[s] * f;
        w.w = w11[s] * f;
        descW[(size_t)rb * NSUB_ + s] = w;
    }
    uint4 a4;
    a4.x = idx[0]; a4.y = idx[1]; a4.z = idx[2]; a4.w = idx[3];
    descA[rb] = a4;
}

// ---------------- main kernel: gload_lds staging, serial per plane --------
__global__ __launch_bounds__(BLK_, 4) void droi_pool_gl(
    const float* __restrict__ features,
    float* __restrict__ out,
    const int* __restrict__ ws)
{
    __shared__ float plane[PLN_];           // 113,584 B -> 1 block/CU

    const int c0  = blockIdx.x * CPB_;      // first channel of this block
    const int b   = blockIdx.y;             // image
    const int tid = threadIdx.x;

    const float4* __restrict__ fbase =
        reinterpret_cast<const float4*>(features + (size_t)b * C_ * HW_);

    // zero the pad tail once; staging only writes [0, HW_), so it stays 0.
    for (int i = HW_ + tid; i < PLN_; i += BLK_) plane[i] = 0.0f;

    const int cnt_b = ws[b];
    const int* __restrict__ list = ws + WS_LIST_OFF_ + b * N_;
    const uint4* __restrict__ descA =
        reinterpret_cast<const uint4*>(ws + WS_DESCA_OFF_I);
    const float4* __restrict__ descW =
        reinterpret_cast<const float4*>(ws + WS_DESCW_OFF_I);

    const int q   = tid / BINS_;            // roi slot within chunk
    const int bin = tid - q * BINS_;        // 0..48
    const bool lane_ok = (q < RPC_);

    for (int p = 0; p < CPB_; ++p) {
        const int c = c0 + p;

        // ---- stage plane c: fire-and-forget direct-to-LDS, no reg dest ----
        {
            const float4* __restrict__ f4 = fbase + (size_t)c * HW4_;
#pragma unroll
            for (int i = 0; i < FULL_ROUNDS_; ++i) {
                const int slot = tid + i * BLK_;
                gload16(f4 + slot, &plane[slot * 4]);
            }
            if (tid < TAIL_THREADS_) {
                const int slot = tid + FULL_ROUNDS_ * BLK_;
                gload16(f4 + slot, &plane[slot * 4]);
            }
        }
        __syncthreads();                    // vmcnt(0) drain -> LDS valid

        // ---- sample plane c via folded descriptors ----
        for (int base = 0; base < cnt_b; base += RPC_) {
            const int idx    = base + q;
            const bool active = lane_ok && (idx < cnt_b);
            if (active) {
                const int r  = list[idx];
                const int rb = r * BINS_ + bin;

                const uint4 a4 = descA[rb];
                const float4* __restrict__ wp = descW + (size_t)rb * NSUB_;

                float acc = 0.0f;
#pragma unroll
                for (int s = 0; s < NSUB_; ++s) {
                    const float4 w = wp[s];
                    const int a = (int)((&a4.x)[s]);
                    const float f00 = plane[a];
                    const float f01 = plane[a + 1];
                    const float f10 = plane[a + W_];
                    const float f11 = plane[a + W_ + 1];
                    acc += w.x * f00 + w.y * f01 + w.z * f10 + w.w * f11;
                }
                out[((size_t)r * C_ + c) * BINS_ + bin] = acc;
            }
        }

        __syncthreads();                    // all reads done before overwrite
    }
}

// ---------------- fallback (round-1 kernel) if ws too small ----------------
__global__ __launch_bounds__(64) void droi_pool_fallback(
    const float* __restrict__ features,
    const float* __restrict__ rois,
    const float* __restrict__ offset,
    float* __restrict__ out)
{
    const int blk  = blockIdx.x;
    const int n    = blk >> 8;
    const int c    = blk & 255;
    const int lane = threadIdx.x;
    if (lane >= BINS_) return;
    const int ph = lane / PW_;
    const int pw = lane % PW_;

    const float r0  = rois[n * 5 + 0];
    const float x1r = rois[n * 5 + 1];
    const float y1r = rois[n * 5 + 2];
    const float x2r = rois[n * 5 + 3];
    const float y2r = rois[n * 5 + 4];
    const int   b   = (int)r0;

    const float sw    = x1r * SS_ - 0.5f;
    const float sh    = y1r * SS_ - 0.5f;
    const float rw    = fmaxf((x2r + 1.0f) * SS_ - 0.5f - sw, 0.1f);
    const float rh    = fmaxf((y2r + 1.0f) * SS_ - 0.5f - sh, 0.1f);
    const float bin_w = rw / PW_;
    const float bin_h = rh / PH_;
    const float sub_w = bin_w / SPP_;
    const float sub_h = bin_h / SPP_;

    const float offx = offset[((n * 2 + 0) * PH_ + ph) * PW_ + pw] * TRANS_STD_;
    const float offy = offset[((n * 2 + 1) * PH_ + ph) * PW_ + pw] * TRANS_STD_;

    const float bx = sw + (float)pw * bin_w + offx * rw;
    const float by = sh + (float)ph * bin_h + offy * rh;

    const float* __restrict__ f =
        features + (size_t)(b * C_ + c) * (size_t)HW_;

    float s = 0.0f;
    int cnt = 0;
#pragma unroll
    for (int ihs = 0; ihs < SPP_; ++ihs) {
#pragma unroll
        for (int iws = 0; iws < SPP_; ++iws) {
            const float x = bx + ((float)iws + 0.5f) * sub_w;
            const float y = by + ((float)ihs + 0.5f) * sub_h;
            const bool valid = (x > -0.5f) && (x < (float)W_ - 0.5f) &&
                               (y > -0.5f) && (y < (float)H_ - 0.5f);
            const float xc = fminf(fmaxf(x, 0.0f), (float)(W_ - 1));
            const float yc = fminf(fmaxf(y, 0.0f), (float)(H_ - 1));
            const float x0f = floorf(xc);
            const float y0f = floorf(yc);
            const float lx = xc - x0f;
            const float ly = yc - y0f;
            const int x0 = (int)x0f;
            const int y0 = (int)y0f;
            const int x1i = min(x0 + 1, W_ - 1);
            const int y1i = min(y0 + 1, H_ - 1);
            const float f00 = f[y0  * W_ + x0 ];
            const float f01 = f[y0  * W_ + x1i];
            const float f10 = f[y1i * W_ + x0 ];
            const float f11 = f[y1i * W_ + x1i];
            const float v = (1.0f - ly) * (1.0f - lx) * f00 +
                            (1.0f - ly) * lx          * f01 +
                            ly          * (1.0f - lx) * f10 +
                            ly          * lx          * f11;
            if (valid) { s += v; cnt += 1; }
        }
    }
    const float res = (cnt > 0) ? (s / (float)cnt) : 0.0f;
    out[(size_t)(n * C_ + c) * BINS_ + lane] = res;
}

extern "C" void kernel_launch(void* const* d_in, const int* in_sizes, int n_in,
                              void* d_out, int out_size, void* d_ws, size_t ws_size,
                              hipStream_t stream) {
    const float* features = (const float*)d_in[0];
    const float* rois     = (const float*)d_in[1];
    const float* offset   = (const float*)d_in[2];
    float*       out      = (float*)d_out;

    if (ws_size >= WS_NEEDED_) {
        int* ws = (int*)d_ws;
        // one merged prologue launch: desc blocks 0..N_-1, list block N_
        hipLaunchKernelGGL(build_all, dim3(N_ + 1), dim3(64), 0, stream,
                           rois, offset, ws);
        // grid: x = channel-group (32), y = image (8); 256 blocks, 1/CU
        // (113.6 KB LDS), 16 waves; per plane: bulk gload_lds -> barrier ->
        // sample -> barrier.
        hipLaunchKernelGGL(droi_pool_gl, dim3(C_ / CPB_, B_), dim3(BLK_),
                           0, stream, features, out, ws);
    } else {
        hipLaunchKernelGGL(droi_pool_fallback, dim3(N_ * C_), dim3(64), 0, stream,
                           features, rois, offset, out);
    }
}